// Round 1
// baseline (1329.320 us; speedup 1.0000x reference)
//
#include <hip/hip_runtime.h>
#include <math.h>

// Problem constants (fixed by the reference): x[64][4096][1024] fp32,
// top-16 along axis 1, mean -> out[64][1024] fp32.
#define BB 64
#define DD 4096
#define NN 1024
#define KK 16
#define SS 8            // d-slices per output (one wave per slice)
#define NT 64           // n-columns per block (one per lane)
#define DSL (DD / SS)   // 512 elements per slice

__device__ __forceinline__ float med3f(float a, float b, float c) {
    return __builtin_amdgcn_fmed3f(a, b, c);
}

// Branchless sorted-insert: v[] descending; insert x keeping top-16.
// v[j] = med3(x, v[j-1], v[j]) == max(min(v[j-1], x), v[j]) when v[j-1] >= v[j].
// Updating j = 15..1 in place uses only old values. 16 VALU ops/element.
__device__ __forceinline__ void insert16(float (&v)[KK], float xx) {
#pragma unroll
    for (int j = KK - 1; j >= 1; --j) v[j] = med3f(xx, v[j - 1], v[j]);
    v[0] = fmaxf(v[0], xx);
}

__global__ __launch_bounds__(512, 8)
void topk_mean_kernel(const float* __restrict__ x, float* __restrict__ out) {
    // [k][slice][lane]: lane-stride 1 -> conflict-free LDS
    __shared__ float lds[KK][SS][NT];

    const int tid    = threadIdx.x;
    const int lane_n = tid & (NT - 1);   // lane index == n offset -> coalesced
    const int slice  = tid >> 6;         // wave index == d-slice
    const int b      = blockIdx.y;
    const int n      = blockIdx.x * NT + lane_n;

    const float* p = x + ((size_t)b * DD + (size_t)slice * DSL) * NN + n;

    float v[KK];
#pragma unroll
    for (int j = 0; j < KK; ++j) v[j] = -INFINITY;

    // Main scan: unroll-8 batched loads (8 outstanding 256B requests/wave),
    // then branchless top-16 update. 512 iterations per thread.
    for (int i = 0; i < DSL; i += 8) {
        float xv[8];
#pragma unroll
        for (int u = 0; u < 8; ++u) xv[u] = p[(size_t)(i + u) * NN];
#pragma unroll
        for (int u = 0; u < 8; ++u) insert16(v, xv[u]);
    }

    // Stage per-slice sorted top-16 lists, then 3-round tree merge.
#pragma unroll
    for (int j = 0; j < KK; ++j) lds[j][slice][lane_n] = v[j];
    __syncthreads();

    for (int half = SS / 2; half >= 1; half >>= 1) {
        if (slice < half) {
#pragma unroll
            for (int j = 0; j < KK; ++j) {
                const float xx = lds[j][slice + half][lane_n];
                insert16(v, xx);
            }
            if (half > 1) {
#pragma unroll
                for (int j = 0; j < KK; ++j) lds[j][slice][lane_n] = v[j];
            }
        }
        __syncthreads();
    }

    if (slice == 0) {
        float s = 0.0f;
#pragma unroll
        for (int j = 0; j < KK; ++j) s += v[j];
        out[(size_t)b * NN + n] = s * (1.0f / 16.0f);  // exact /16
    }
}

extern "C" void kernel_launch(void* const* d_in, const int* in_sizes, int n_in,
                              void* d_out, int out_size, void* d_ws, size_t ws_size,
                              hipStream_t stream) {
    const float* x = (const float*)d_in[0];
    float* out    = (float*)d_out;
    dim3 grid(NN / NT, BB);  // 16 n-tiles x 64 batches = 1024 blocks
    topk_mean_kernel<<<grid, dim3(512, 1, 1), 0, stream>>>(x, out);
}